// Round 1
// baseline (4124.823 us; speedup 1.0000x reference)
//
#include <hip/hip_runtime.h>

static constexpr int CH   = 256;
static constexpr int NH   = 4;
static constexpr int DQK  = 32;
static constexpr int DV   = 64;
static constexpr int QKR  = 128;
static constexpr int SY   = 48;
static constexpr int SX   = 48;
static constexpr int SZ   = 48;
static constexpr int NPEN = SY * SX;     // 2304
static constexpr int NPOS = NPEN * SZ;   // 110592
static constexpr int ZT    = 16;
static constexpr int NTILE = 3;
static constexpr int G     = 32;         // channels per staging group
static constexpr int NG    = 8;
static constexpr int XH_ZP = 19;         // xh[G][9][XH_ZP]
static constexpr int W_P   = 17;         // wexp[128][W_P]
static constexpr int V_P   = 17;         // vsm[256][V_P]
static constexpr int XC_P  = 20;         // stage3 xcen[256][XC_P]
static constexpr int LQ_P  = 20;         // stage3 qsm[128][LQ_P]
static constexpr int PART_F = NH*DQK*DV + NH*DQK;  // 8320 floats per partial

// ---------------------------------------------------------------------------
// Stage 1: per-chunk partial kv[h][kc][dv] = sum_n exp(Wk x)_kc * v_dv,
//          partial s[h][kc] = sum_n exp(Wk x)_kc.   (max-free: |logit|<~3)
// ---------------------------------------------------------------------------
__global__ __launch_bounds__(256) void k_stage1(
    const float* __restrict__ x, const float* __restrict__ Wk,
    const float* __restrict__ Wv, const float* __restrict__ bv,
    float* __restrict__ partials, int K)
{
  __shared__ float xh[G * 9 * XH_ZP];   // halo tile for one channel group
  __shared__ float wexp[QKR * W_P];     // exp(k-logit) for this z-tile
  __shared__ float vsm[CH * V_P];       // depthwise-conv v for this z-tile

  const int t   = threadIdx.x;
  const int bid = blockIdx.x;
  const int b   = bid / K;
  const int k0  = bid % K;

  // kv-phase role: each thread owns (head, {kc0,kc0+16}, dv0..dv0+15)
  const int ht  = t >> 6;
  const int l   = t & 63;
  const int kc0 = l >> 2;
  const int dv0 = (l & 3) << 4;

  float accA[16], accB[16];
  float sA = 0.f, sB = 0.f;
#pragma unroll
  for (int j = 0; j < 16; ++j) { accA[j] = 0.f; accB[j] = 0.f; }

  const float* xb = x + (size_t)b * CH * NPOS;

  const int lz = t & 15;   // logit-phase role
  const int rb = t >> 4;

  for (int p = k0; p < NPEN; p += K) {
    const int py = p / SX;
    const int px = p % SX;
    for (int zt = 0; zt < NTILE; ++zt) {
      const int z0 = zt * ZT;
      float facc[8];
#pragma unroll
      for (int r = 0; r < 8; ++r) facc[r] = 0.f;

      for (int cg = 0; cg < NG; ++cg) {
        const int cbase = cg * G;
        __syncthreads();                       // xh (and vsm on cg=0) free
        // --- stage halo: G ch x 9 pencils x 18 z (z0-1 .. z0+16) ---
        for (int i = t; i < G * 9 * 18; i += 256) {
          const int row = i / 18;
          const int zi  = i - row * 18;
          const int c   = row / 9;
          const int pp  = row - c * 9;
          const int dy  = pp / 3 - 1, dx = pp % 3 - 1;
          const int yy  = py + dy, xx = px + dx, zz = z0 - 1 + zi;
          float v = 0.f;
          if ((unsigned)yy < (unsigned)SY && (unsigned)xx < (unsigned)SX &&
              (unsigned)zz < (unsigned)SZ)
            v = xb[(size_t)(cbase + c) * NPOS + (size_t)(yy * SX + xx) * SZ + zz];
          xh[(c * 9 + pp) * XH_ZP + zi] = v;
        }
        __syncthreads();
        // --- depthwise conv for this group: G ch x 16 z ---
        for (int i = t; i < G * ZT; i += 256) {
          const int c  = i >> 4;
          const int z  = i & 15;
          const int cc = cbase + c;
          float vv = bv[cc];
          const float* wv = Wv + cc * 27;
#pragma unroll
          for (int ty = 0; ty < 3; ++ty)
#pragma unroll
            for (int tx = 0; tx < 3; ++tx) {
              const float* xr = &xh[(c * 9 + ty * 3 + tx) * XH_ZP + z];
              const float* wp = wv + (ty * 3 + tx) * 3;
              vv += wp[0] * xr[0] + wp[1] * xr[1] + wp[2] * xr[2];
            }
          vsm[cc * V_P + z] = vv;
        }
        // --- logit partial dot over this group's channels ---
        for (int cl = 0; cl < G; cl += 4) {
          const float xv0 = xh[((cl + 0) * 9 + 4) * XH_ZP + 1 + lz];
          const float xv1 = xh[((cl + 1) * 9 + 4) * XH_ZP + 1 + lz];
          const float xv2 = xh[((cl + 2) * 9 + 4) * XH_ZP + 1 + lz];
          const float xv3 = xh[((cl + 3) * 9 + 4) * XH_ZP + 1 + lz];
#pragma unroll
          for (int rr = 0; rr < 8; ++rr) {
            const int r = rb * 8 + rr;
            const float4 wk = *(const float4*)&Wk[r * CH + cbase + cl];
            facc[rr] += wk.x * xv0 + wk.y * xv1 + wk.z * xv2 + wk.w * xv3;
          }
        }
      }
      // --- exp + share weights ---
#pragma unroll
      for (int rr = 0; rr < 8; ++rr) {
        const int r = rb * 8 + rr;
        wexp[r * W_P + lz] = __expf(facc[rr]);
      }
      __syncthreads();                         // vsm + wexp ready
      // --- kv accumulation (register accumulators) ---
      const float* wrow0 = &wexp[(ht * DQK + kc0) * W_P];
      const float* wrow1 = &wexp[(ht * DQK + kc0 + 16) * W_P];
      const float* vbase = &vsm[(ht * DV + dv0) * V_P];
      for (int z = 0; z < ZT; ++z) {
        const float w0 = wrow0[z];
        const float w1 = wrow1[z];
        sA += w0; sB += w1;
#pragma unroll
        for (int j = 0; j < 16; ++j) {
          const float vv = vbase[j * V_P + z];
          accA[j] += w0 * vv;
          accB[j] += w1 * vv;
        }
      }
    }
  }

  float* pb = partials + (size_t)bid * PART_F;
#pragma unroll
  for (int j = 0; j < 16; ++j) {
    pb[ht * 2048 + (kc0)      * 64 + dv0 + j] = accA[j];
    pb[ht * 2048 + (kc0 + 16) * 64 + dv0 + j] = accB[j];
  }
  if ((l & 3) == 0) {
    pb[8192 + ht * DQK + kc0]      = sA;
    pb[8192 + ht * DQK + kc0 + 16] = sB;
  }
}

// ---------------------------------------------------------------------------
// Stage 2a: reduce K block-partials in 32 chunks per (b,h)
// ---------------------------------------------------------------------------
__global__ __launch_bounds__(256) void k_reduce_a(
    const float* __restrict__ partials, float* __restrict__ partial2, int K)
{
  const int bid   = blockIdx.x;         // grid = B*NH*32 = 256
  const int chunk = bid & 31;
  const int h     = (bid >> 5) & 3;
  const int b     = bid >> 7;
  const int kpc   = (K + 31) / 32;
  const int ks    = chunk * kpc;
  const int ke    = min(K, ks + kpc);
  for (int i = threadIdx.x; i < 2080; i += 256) {
    const size_t off = (i < 2048) ? ((size_t)h * 2048 + i)
                                  : ((size_t)8192 + h * 32 + (i - 2048));
    float s = 0.f;
    for (int k = ks; k < ke; ++k)
      s += partials[(size_t)(b * K + k) * PART_F + off];
    partial2[((size_t)((b * NH + h) * 32 + chunk)) * 2080 + i] = s;
  }
}

// ---------------------------------------------------------------------------
// Stage 2b: final reduce + normalize: kvn = P / S
// ---------------------------------------------------------------------------
__global__ __launch_bounds__(256) void k_reduce_b(
    const float* __restrict__ partial2, float* __restrict__ kvn)
{
  const int h = blockIdx.x & 3;        // grid = B*NH = 8
  const int b = blockIdx.x >> 2;
  __shared__ float ssum[DQK];
  for (int i = threadIdx.x; i < DQK; i += 256) {
    float s = 0.f;
    for (int c = 0; c < 32; ++c)
      s += partial2[((size_t)((b * NH + h) * 32 + c)) * 2080 + 2048 + i];
    ssum[i] = s;
  }
  __syncthreads();
  for (int i = threadIdx.x; i < 2048; i += 256) {
    float s = 0.f;
    for (int c = 0; c < 32; ++c)
      s += partial2[((size_t)((b * NH + h) * 32 + c)) * 2080 + i];
    kvn[(size_t)(b * NH + h) * 2048 + i] = s / ssum[i >> 6];
  }
}

// ---------------------------------------------------------------------------
// Stage 3: out[co,n] = (1/(1+eps)) * sum_kc softmax32(Wq x)_kc * kvn[h,kc,dv]
// ---------------------------------------------------------------------------
__global__ __launch_bounds__(256) void k_stage3(
    const float* __restrict__ x, const float* __restrict__ Wq,
    const float* __restrict__ kvn, float* __restrict__ out)
{
  __shared__ float xcen[CH * XC_P];
  __shared__ float qsm[QKR * LQ_P];
  __shared__ float kvl[NH * DQK * DV];

  const int t   = threadIdx.x;
  const int bid = blockIdx.x;
  const int b   = bid / NPEN;
  const int p   = bid % NPEN;
  const float* xb = x + (size_t)b * CH * NPOS;
  const size_t poff = (size_t)p * SZ;

  for (int i = t; i < NH * DQK * DV; i += 256)
    kvl[i] = kvn[(size_t)b * (NH * DQK * DV) + i];

  const int lz = t & 15;
  const int rb = t >> 4;

  // num-phase roles
  const int z4  = (t & 3) << 2;
  const int cog = t >> 2;
  const int co  = cog << 2;
  const int h   = co >> 6;
  const int dvq = co & 63;

  const float scale = 1.f / (1.f + 1e-6f);

  for (int zt = 0; zt < NTILE; ++zt) {
    const int z0 = zt * ZT;
    __syncthreads();
    // --- stage center pencil: 256 ch x 16 z, float4 ---
    for (int i = t; i < CH * 4; i += 256) {
      const int c  = i >> 2;
      const int zq = (i & 3) << 2;
      const float4 vv = *(const float4*)&xb[(size_t)c * NPOS + poff + z0 + zq];
      *(float4*)&xcen[c * XC_P + zq] = vv;
    }
    __syncthreads();
    // --- q logits ---
    float facc[8];
#pragma unroll
    for (int r = 0; r < 8; ++r) facc[r] = 0.f;
    for (int cl = 0; cl < CH; cl += 4) {
      const float xv0 = xcen[(cl + 0) * XC_P + lz];
      const float xv1 = xcen[(cl + 1) * XC_P + lz];
      const float xv2 = xcen[(cl + 2) * XC_P + lz];
      const float xv3 = xcen[(cl + 3) * XC_P + lz];
#pragma unroll
      for (int rr = 0; rr < 8; ++rr) {
        const int r = rb * 8 + rr;
        const float4 wq = *(const float4*)&Wq[r * CH + cl];
        facc[rr] += wq.x * xv0 + wq.y * xv1 + wq.z * xv2 + wq.w * xv3;
      }
    }
#pragma unroll
    for (int rr = 0; rr < 8; ++rr)
      qsm[(rb * 8 + rr) * LQ_P + lz] = facc[rr];
    __syncthreads();
    // --- softmax over 32 kc per (head, z): 64 groups x 4 lanes ---
    {
      const int g  = t >> 2;
      const int l4 = t & 3;
      const int hh = g >> 4;
      const int zz = g & 15;
      float vals[8];
      float m = -1e30f;
#pragma unroll
      for (int j = 0; j < 8; ++j) {
        vals[j] = qsm[(hh * DQK + l4 + j * 4) * LQ_P + zz];
        m = fmaxf(m, vals[j]);
      }
      m = fmaxf(m, __shfl_xor(m, 1));
      m = fmaxf(m, __shfl_xor(m, 2));
      float se = 0.f;
#pragma unroll
      for (int j = 0; j < 8; ++j) { vals[j] = __expf(vals[j] - m); se += vals[j]; }
      se += __shfl_xor(se, 1);
      se += __shfl_xor(se, 2);
      const float inv = 1.f / se;
#pragma unroll
      for (int j = 0; j < 8; ++j)
        qsm[(hh * DQK + l4 + j * 4) * LQ_P + zz] = vals[j] * inv;
    }
    __syncthreads();
    // --- num: acc[dv 4][z 4] ---
    float acc[4][4];
#pragma unroll
    for (int a = 0; a < 4; ++a)
#pragma unroll
      for (int c2 = 0; c2 < 4; ++c2) acc[a][c2] = 0.f;
    const float* kvh = &kvl[h * DQK * DV];
    for (int kc = 0; kc < DQK; ++kc) {
      const float4 kf = *(const float4*)&kvh[kc * DV + dvq];
      const float4 qf = *(const float4*)&qsm[(h * DQK + kc) * LQ_P + z4];
      acc[0][0] += kf.x * qf.x; acc[0][1] += kf.x * qf.y; acc[0][2] += kf.x * qf.z; acc[0][3] += kf.x * qf.w;
      acc[1][0] += kf.y * qf.x; acc[1][1] += kf.y * qf.y; acc[1][2] += kf.y * qf.z; acc[1][3] += kf.y * qf.w;
      acc[2][0] += kf.z * qf.x; acc[2][1] += kf.z * qf.y; acc[2][2] += kf.z * qf.z; acc[2][3] += kf.z * qf.w;
      acc[3][0] += kf.w * qf.x; acc[3][1] += kf.w * qf.y; acc[3][2] += kf.w * qf.z; acc[3][3] += kf.w * qf.w;
    }
#pragma unroll
    for (int j = 0; j < 4; ++j) {
      float4 o;
      o.x = acc[j][0] * scale; o.y = acc[j][1] * scale;
      o.z = acc[j][2] * scale; o.w = acc[j][3] * scale;
      *(float4*)&out[((size_t)b * CH + co + j) * NPOS + poff + z0 + z4] = o;
    }
  }
}

// ---------------------------------------------------------------------------
extern "C" void kernel_launch(void* const* d_in, const int* in_sizes, int n_in,
                              void* d_out, int out_size, void* d_ws, size_t ws_size,
                              hipStream_t stream)
{
  const float* x  = (const float*)d_in[0];
  const float* Wq = (const float*)d_in[1];
  const float* Wk = (const float*)d_in[2];
  const float* Wv = (const float*)d_in[3];
  const float* bv = (const float*)d_in[4];
  float* out = (float*)d_out;
  float* ws  = (float*)d_ws;

  // ws layout: [kvn 16384 f][partial2 8*32*2080 f][partials 2K*8320 f]
  float* kvn      = ws;
  float* partial2 = ws + 16384;
  float* partials = partial2 + 8 * 32 * 2080;
  const long used  = 16384 + 8 * 32 * 2080;
  long avail = (long)(ws_size / 4) - used;
  int K = (int)(avail / (2 * PART_F));
  if (K > 432) K = 432;
  if (K < 1)  K = 1;

  k_stage1 <<<dim3(2 * K),        dim3(256), 0, stream>>>(x, Wk, Wv, bv, partials, K);
  k_reduce_a<<<dim3(2 * NH * 32), dim3(256), 0, stream>>>(partials, partial2, K);
  k_reduce_b<<<dim3(2 * NH),      dim3(256), 0, stream>>>(partial2, kvn);
  k_stage3 <<<dim3(2 * NPEN),     dim3(256), 0, stream>>>(x, Wq, kvn, out);
}

// Round 3
// 1404.904 us; speedup vs baseline: 2.9360x; 2.9360x over previous
//
#include <hip/hip_runtime.h>
#include <hip/hip_bf16.h>

static constexpr int CH   = 256;
static constexpr int NHD  = 4;
static constexpr int DQK  = 32;
static constexpr int DV   = 64;
static constexpr int SY = 48, SX = 48, SZ = 48;
static constexpr int NPEN = SY * SX;     // 2304
static constexpr int NPOS = NPEN * SZ;   // 110592
static constexpr int PART_F = NHD*DQK*DV + NHD*DQK;  // 8320

// ---------------------------------------------------------------------------
// Prep: transpose Wq, Wk (128x256 -> 256x128) so weight reads are contiguous
// per-channel and wave-uniform (scalar-load friendly).
// ---------------------------------------------------------------------------
__global__ __launch_bounds__(256) void k_prep(
    const float* __restrict__ Wq, const float* __restrict__ Wk,
    float* __restrict__ WqT, float* __restrict__ WkT)
{
  int i = blockIdx.x * 256 + threadIdx.x;
  if (i < 128 * 256) {
    int c = i >> 7, r = i & 127;
    WqT[i] = Wq[r * 256 + c];
    WkT[i] = Wk[r * 256 + c];
  }
}

// ---------------------------------------------------------------------------
// Depthwise 3x3x3 conv + bias -> v (bf16) for a y-slab [y0s, y0s+ys).
// Block: (b, c, y-tile of 4 rows). LDS stages rows+2 y-rows zero-padded.
// ---------------------------------------------------------------------------
__global__ __launch_bounds__(256) void k_conv(
    const float* __restrict__ x, const float* __restrict__ Wv,
    const float* __restrict__ bv, __hip_bfloat16* __restrict__ vbuf,
    int y0s, int ys, int nyt)
{
  __shared__ float xs[6 * 50 * 52];   // 62.4 KB, rows 16B-aligned (52 words)
  const int bid = blockIdx.x;
  const int yt  = bid % nyt;
  const int c   = (bid / nyt) & 255;
  const int b   = bid / (nyt * 256);
  const int y0c = y0s + yt * 4;
  const int rows = min(4, y0s + ys - y0c);
  const float* xc = x + (size_t)(b * CH + c) * NPOS;

  const int tot = (rows + 2) * 2600;
  for (int i = threadIdx.x; i < tot; i += 256) {
    const int r = i / 2600, rem = i % 2600;
    const int px = rem / 52, pz = rem % 52;
    if (pz < 50) {
      const int y = y0c - 1 + r;
      float v = 0.f;
      if (y >= 0 && y < SY && px >= 1 && px <= 48 && pz >= 1 && pz <= 48)
        v = xc[(size_t)y * NPEN + (px - 1) * 48 + (pz - 1)];
      xs[i] = v;
    }
  }
  float w[27];
  const float* wv = Wv + c * 27;
#pragma unroll
  for (int j = 0; j < 27; ++j) w[j] = wv[j];
  const float bias = bv[c];
  __syncthreads();

  const int nout = rows * 576;   // z-quads
  for (int i = threadIdx.x; i < nout; i += 256) {
    const int yy = i / 576, rem = i % 576;
    const int xx = rem / 12, zb = (rem % 12) * 4;
    float a0 = bias, a1 = bias, a2 = bias, a3 = bias;
#pragma unroll
    for (int a = 0; a < 3; ++a)
#pragma unroll
      for (int bb = 0; bb < 3; ++bb) {
        const float* rowp = &xs[(yy + a) * 2600 + (xx + bb) * 52 + zb];
        const float4 f0 = *(const float4*)rowp;
        const float2 f1 = *(const float2*)(rowp + 4);
        const float w0 = w[(a*3+bb)*3 + 0], w1 = w[(a*3+bb)*3 + 1], w2 = w[(a*3+bb)*3 + 2];
        a0 += w0*f0.x + w1*f0.y + w2*f0.z;
        a1 += w0*f0.y + w1*f0.z + w2*f0.w;
        a2 += w0*f0.z + w1*f0.w + w2*f1.x;
        a3 += w0*f0.w + w1*f1.x + w2*f1.y;
      }
    const size_t o = (size_t)(b * CH + c) * ((size_t)ys * NPEN) +
                     (size_t)(y0c - y0s + yy) * NPEN + xx * 48 + zb;
    vbuf[o + 0] = __float2bfloat16(a0);
    vbuf[o + 1] = __float2bfloat16(a1);
    vbuf[o + 2] = __float2bfloat16(a2);
    vbuf[o + 3] = __float2bfloat16(a3);
  }
}

// ---------------------------------------------------------------------------
// k_kv: per 64-position tile: k-logit GEMV (lane=position, wave=head),
// exp, then kv[kc][dv] accumulation via readlane broadcast. No barriers.
// All vl accesses are u32-typed (no ushort punning -> no TBAA reordering).
// ---------------------------------------------------------------------------
__global__ __launch_bounds__(256) void k_kv(
    const float* __restrict__ x, const float* __restrict__ WkT,
    const __hip_bfloat16* __restrict__ vbuf, float* __restrict__ partials,
    int y0s, int ys, int first, int nbh)
{
  __shared__ unsigned vl[64 * 129];   // 33 KB: [n][c-pairs], stride 129 u32
  const int t = threadIdx.x;
  const int lane = t & 63;
  const int h = __builtin_amdgcn_readfirstlane(t >> 6);
  const int bid = blockIdx.x;
  const int b  = (bid >= nbh) ? 1 : 0;
  const int bh = bid - b * nbh;
  const int ntiles = ys * (NPEN / 64);

  float kvacc[32], sS[32];
#pragma unroll
  for (int j = 0; j < 32; ++j) { kvacc[j] = 0.f; sS[j] = 0.f; }

  const size_t Nsl = (size_t)ys * NPEN;
  const float* xb = x + (size_t)b * CH * NPOS + (size_t)y0s * NPEN;
  const ushort* vbu = (const ushort*)(vbuf) + (size_t)(b * CH + h * DV) * Nsl;

  for (int tile = bh; tile < ntiles; tile += nbh) {
    const int n0 = tile * 64;
    // --- phase 1: k logits (32 rows of this head) ---
    float wr[32];
#pragma unroll
    for (int j = 0; j < 32; ++j) wr[j] = 0.f;
    const float* xp = xb + n0 + lane;
#pragma unroll 4
    for (int c = 0; c < CH; ++c) {
      const float xv = xp[(size_t)c * NPOS];
      const float* wk = WkT + c * 128 + h * 32;
#pragma unroll
      for (int j = 0; j < 32; ++j) wr[j] = fmaf(wk[j], xv, wr[j]);
    }
    // --- exp (max-free: |logit| < ~3) + S partial ---
#pragma unroll
    for (int j = 0; j < 32; ++j) { wr[j] = __expf(wr[j]); sS[j] += wr[j]; }
    // --- stage own head's v (64 ch x 64 pos) transposed into LDS (u32 pairs) ---
#pragma unroll
    for (int c2 = 0; c2 < 32; ++c2) {
      const unsigned q0 = vbu[(size_t)(2 * c2)     * Nsl + n0 + lane];
      const unsigned q1 = vbu[(size_t)(2 * c2 + 1) * Nsl + n0 + lane];
      vl[lane * 129 + h * 32 + c2] = q0 | (q1 << 16);
    }
    __asm__ __volatile__("" ::: "memory");   // pin LDS write<->read order
    // --- phase 3: kv[kc][dv=lane] += wexp(kc,n) * v(dv,n) ---
    const int cp = h * 32 + (lane >> 1);
    const bool hi = (lane & 1);
    for (int n = 0; n < 64; ++n) {
      const unsigned pair = vl[n * 129 + cp];
      const float vv = __uint_as_float(hi ? (pair & 0xffff0000u)
                                          : (pair << 16));
#pragma unroll
      for (int kc = 0; kc < 32; ++kc) {
        const float w = __uint_as_float(
            (unsigned)__builtin_amdgcn_readlane((int)__float_as_uint(wr[kc]), n));
        kvacc[kc] = fmaf(w, vv, kvacc[kc]);
      }
    }
    __asm__ __volatile__("" ::: "memory");   // reads done before next-tile writes
  }

  // --- write kv partials (coalesced), RMW-accumulate across slabs ---
  float* pb = partials + (size_t)bid * PART_F + h * 2048;
  if (first) {
#pragma unroll
    for (int kc = 0; kc < 32; ++kc) pb[kc * 64 + lane] = kvacc[kc];
  } else {
#pragma unroll
    for (int kc = 0; kc < 32; ++kc) pb[kc * 64 + lane] += kvacc[kc];
  }
  // --- wave-reduce S and store via lane 0 ---
#pragma unroll
  for (int kc = 0; kc < 32; ++kc) {
    float s = sS[kc];
    s += __shfl_xor(s, 1);  s += __shfl_xor(s, 2);  s += __shfl_xor(s, 4);
    s += __shfl_xor(s, 8);  s += __shfl_xor(s, 16); s += __shfl_xor(s, 32);
    sS[kc] = s;
  }
  if (lane == 0) {
    float* ps = partials + (size_t)bid * PART_F + 8192 + h * 32;
    if (first) {
#pragma unroll
      for (int kc = 0; kc < 32; ++kc) ps[kc] = sS[kc];
    } else {
#pragma unroll
      for (int kc = 0; kc < 32; ++kc) ps[kc] += sS[kc];
    }
  }
}

// ---------------------------------------------------------------------------
// Reduce partials over blocks; normalize kv by S (k-softmax denominator).
// ---------------------------------------------------------------------------
__global__ __launch_bounds__(256) void k_reduce(
    const float* __restrict__ partials, float* __restrict__ kvn, int nbh)
{
  const int bid = blockIdx.x;            // 64 = b(2) x h(4) x chunk(8)
  const int chunk = bid & 7, h = (bid >> 3) & 3, b = bid >> 5;
  __shared__ float Ssh[32];
  const int t = threadIdx.x;
  const float* pbase = partials + (size_t)(b ? nbh : 0) * PART_F;
  if (t < 32) {
    float s = 0.f;
    for (int k = 0; k < nbh; ++k)
      s += pbase[(size_t)k * PART_F + 8192 + h * 32 + t];
    Ssh[t] = s;
  }
  __syncthreads();
  const int e = chunk * 256 + t;         // 0..2047
  float s = 0.f;
  for (int k = 0; k < nbh; ++k)
    s += pbase[(size_t)k * PART_F + h * 2048 + e];
  kvn[(size_t)(b * NHD + h) * 2048 + e] = s / Ssh[e >> 6];
}

// ---------------------------------------------------------------------------
// k_out: q GEMV + lane-local softmax(32) + out = q_sm · kvn, coalesced stores.
// ---------------------------------------------------------------------------
__global__ __launch_bounds__(256) void k_out(
    const float* __restrict__ x, const float* __restrict__ WqT,
    const float* __restrict__ kvn, float* __restrict__ out)
{
  const int t = threadIdx.x, lane = t & 63;
  const int h = __builtin_amdgcn_readfirstlane(t >> 6);
  const int bid = blockIdx.x;
  const int b  = bid / (NPOS / 64);
  const int n0 = (bid % (NPOS / 64)) * 64;
  const float* xb = x + (size_t)b * CH * NPOS + n0 + lane;

  float qa[32];
#pragma unroll
  for (int j = 0; j < 32; ++j) qa[j] = 0.f;
#pragma unroll 4
  for (int c = 0; c < CH; ++c) {
    const float xv = xb[(size_t)c * NPOS];
    const float* wq = WqT + c * 128 + h * 32;
#pragma unroll
    for (int j = 0; j < 32; ++j) qa[j] = fmaf(wq[j], xv, qa[j]);
  }
  // lane-local softmax over 32 channels
  float m = qa[0];
#pragma unroll
  for (int j = 1; j < 32; ++j) m = fmaxf(m, qa[j]);
  float se = 0.f;
#pragma unroll
  for (int j = 0; j < 32; ++j) { qa[j] = __expf(qa[j] - m); se += qa[j]; }
  const float sc = 1.f / (se * (1.f + 1e-6f));   // folds Z==1 and eps
#pragma unroll
  for (int j = 0; j < 32; ++j) qa[j] *= sc;

  float oa[64];
#pragma unroll
  for (int d = 0; d < 64; ++d) oa[d] = 0.f;
  const float* kvh = kvn + (size_t)(b * NHD + h) * 2048;
#pragma unroll
  for (int kc = 0; kc < 32; ++kc) {
    const float* kr = kvh + kc * 64;
#pragma unroll
    for (int d = 0; d < 64; ++d) oa[d] = fmaf(qa[kc], kr[d], oa[d]);
  }
  float* ob = out + (size_t)(b * CH + h * DV) * NPOS + n0 + lane;
#pragma unroll
  for (int d = 0; d < 64; ++d) ob[(size_t)d * NPOS] = oa[d];
}

// ---------------------------------------------------------------------------
extern "C" void kernel_launch(void* const* d_in, const int* in_sizes, int n_in,
                              void* d_out, int out_size, void* d_ws, size_t ws_size,
                              hipStream_t stream)
{
  const float* x  = (const float*)d_in[0];
  const float* Wq = (const float*)d_in[1];
  const float* Wk = (const float*)d_in[2];
  const float* Wv = (const float*)d_in[3];
  const float* bv = (const float*)d_in[4];
  float* out = (float*)d_out;
  float* ws  = (float*)d_ws;

  // ws layout (f32 words): WqT 32768 | WkT 32768 | kvn 8192 | partials nb*8320 | vbuf (bf16)
  float* WqT = ws;
  float* WkT = ws + 32768;
  float* kvn = ws + 65536;
  float* partials = ws + 73728;

  const size_t wsf = ws_size / 4;
  static const int cand[][2] = {
    {1024,48},{1024,24},{512,24},{1024,12},{1024,6},{512,12},
    {512,6},{512,3},{256,6},{256,3},{256,1},{128,1},{64,1},{32,1}};
  int nb = 32, ys = 1;
  for (int i = 0; i < 14; ++i) {
    const size_t need = 73728 + (size_t)cand[i][0] * PART_F
                      + (size_t)cand[i][1] * 589824;   // ys * 2*256*2304/2 words
    if (need <= wsf) { nb = cand[i][0]; ys = cand[i][1]; break; }
  }
  __hip_bfloat16* vbuf = (__hip_bfloat16*)(ws + 73728 + (size_t)nb * PART_F);

  k_prep<<<128, 256, 0, stream>>>(Wq, Wk, WqT, WkT);

  const int nslab = 48 / ys;
  const int nyt = (ys + 3) / 4;
  for (int s = 0; s < nslab; ++s) {
    k_conv<<<2 * 256 * nyt, 256, 0, stream>>>(x, Wv, bv, vbuf, s * ys, ys, nyt);
    k_kv  <<<nb,            256, 0, stream>>>(x, WkT, vbuf, partials,
                                              s * ys, ys, (s == 0) ? 1 : 0, nb / 2);
  }
  k_reduce<<<64,               256, 0, stream>>>(partials, kvn, nb / 2);
  k_out  <<<2 * (NPOS / 64),   256, 0, stream>>>(x, WqT, kvn, out);
}

// Round 4
// 931.424 us; speedup vs baseline: 4.4285x; 1.5083x over previous
//
#include <hip/hip_runtime.h>
#include <hip/hip_bf16.h>

static constexpr int CH   = 256;
static constexpr int NHD  = 4;
static constexpr int DQK  = 32;
static constexpr int DV   = 64;
static constexpr int SY = 48, SX = 48, SZ = 48;
static constexpr int NPEN = SY * SX;     // 2304
static constexpr int NPOS = NPEN * SZ;   // 110592
static constexpr int PART_F = NHD*DQK*DV + NHD*DQK;  // 8320

// ---------------------------------------------------------------------------
// Prep: transpose Wq, Wk (128x256 -> 256x128).
// ---------------------------------------------------------------------------
__global__ __launch_bounds__(256) void k_prep(
    const float* __restrict__ Wq, const float* __restrict__ Wk,
    float* __restrict__ WqT, float* __restrict__ WkT)
{
  int i = blockIdx.x * 256 + threadIdx.x;
  if (i < 128 * 256) {
    int c = i >> 7, r = i & 127;
    WqT[i] = Wq[r * 256 + c];
    WkT[i] = Wk[r * 256 + c];
  }
}

// ---------------------------------------------------------------------------
// Depthwise 3x3x3 conv + bias -> v (bf16), register-rolling window, no LDS.
// Thread = (b, c, x, z-quad); loops y with 3-phase row rotation.
// ---------------------------------------------------------------------------
__global__ __launch_bounds__(256) void k_conv(
    const float* __restrict__ x, const float* __restrict__ Wv,
    const float* __restrict__ bv, __hip_bfloat16* __restrict__ vbuf,
    int y0s, int ys)
{
  const int gid = blockIdx.x * 256 + threadIdx.x;   // 2*256*576 total
  const int zq  = gid % 12;
  const int xx  = (gid / 12) % 48;
  const int c   = (gid / 576) & 255;
  const int b   = gid / 147456;
  const int zb  = zq * 4;

  const float* xc = x + (size_t)(b * CH + c) * NPOS;
  float w[27];
  {
    const float* wv = Wv + c * 27;
#pragma unroll
    for (int j = 0; j < 27; ++j) w[j] = wv[j];
  }
  const float bias = bv[c];

  const bool zlo = (zb > 0);
  const bool zhi = (zq < 11);
  bool colok[3];
  int  coloff[3];
#pragma unroll
  for (int dx = 0; dx < 3; ++dx) {
    const int xcol = xx - 1 + dx;
    colok[dx]  = (xcol >= 0) && (xcol < SX);
    coloff[dx] = xcol * SZ + zb;
  }

  float A[18], B[18], C[18];

#define LOADROW(R, yy_)                                                        \
  {                                                                            \
    const int y_ = (yy_);                                                      \
    const bool yok_ = (y_ >= 0) && (y_ < SY);                                  \
    const float* rowp_ = xc + (size_t)y_ * NPEN;                               \
    _Pragma("unroll")                                                          \
    for (int dx = 0; dx < 3; ++dx) {                                           \
      float m0, m1, m2, m3, zm, zp;                                            \
      if (yok_ && colok[dx]) {                                                 \
        const float* bp_ = rowp_ + coloff[dx];                                 \
        const float4 m_ = *(const float4*)bp_;                                 \
        m0 = m_.x; m1 = m_.y; m2 = m_.z; m3 = m_.w;                            \
        zm = zlo ? bp_[-1] : 0.f;                                              \
        zp = zhi ? bp_[4]  : 0.f;                                              \
      } else { m0 = m1 = m2 = m3 = 0.f; zm = 0.f; zp = 0.f; }                  \
      R[dx*6+0] = zm; R[dx*6+1] = m0; R[dx*6+2] = m1;                          \
      R[dx*6+3] = m2; R[dx*6+4] = m3; R[dx*6+5] = zp;                          \
    }                                                                          \
  }

#define CONVOUT(R0, R1, R2, yy_)                                               \
  {                                                                            \
    float a0 = bias, a1 = bias, a2 = bias, a3 = bias;                          \
    _Pragma("unroll")                                                          \
    for (int kx = 0; kx < 3; ++kx) {                                           \
      _Pragma("unroll")                                                        \
      for (int kz = 0; kz < 3; ++kz) {                                         \
        const float w0_ = w[(0*3+kx)*3+kz];                                    \
        const float w1_ = w[(1*3+kx)*3+kz];                                    \
        const float w2_ = w[(2*3+kx)*3+kz];                                    \
        a0 = fmaf(w0_, R0[kx*6+kz+0], a0); a0 = fmaf(w1_, R1[kx*6+kz+0], a0);  \
        a0 = fmaf(w2_, R2[kx*6+kz+0], a0);                                     \
        a1 = fmaf(w0_, R0[kx*6+kz+1], a1); a1 = fmaf(w1_, R1[kx*6+kz+1], a1);  \
        a1 = fmaf(w2_, R2[kx*6+kz+1], a1);                                     \
        a2 = fmaf(w0_, R0[kx*6+kz+2], a2); a2 = fmaf(w1_, R1[kx*6+kz+2], a2);  \
        a2 = fmaf(w2_, R2[kx*6+kz+2], a2);                                     \
        a3 = fmaf(w0_, R0[kx*6+kz+3], a3); a3 = fmaf(w1_, R1[kx*6+kz+3], a3);  \
        a3 = fmaf(w2_, R2[kx*6+kz+3], a3);                                     \
      }                                                                        \
    }                                                                          \
    const size_t o_ = (size_t)(b * CH + c) * ((size_t)ys * NPEN) +             \
                      (size_t)((yy_) - y0s) * NPEN + xx * SZ + zb;             \
    union { unsigned u[2]; } pk_;                                              \
    pk_.u[0] = (((unsigned)__bfloat16_as_ushort(__float2bfloat16(a1))) << 16)  \
             | (unsigned)__bfloat16_as_ushort(__float2bfloat16(a0));           \
    pk_.u[1] = (((unsigned)__bfloat16_as_ushort(__float2bfloat16(a3))) << 16)  \
             | (unsigned)__bfloat16_as_ushort(__float2bfloat16(a2));           \
    *(uint2*)&vbuf[o_] = *(const uint2*)pk_.u;                                 \
  }

  LOADROW(A, y0s - 1)
  LOADROW(B, y0s)
  for (int yy = 0; yy < ys; yy += 3) {
    const int y = y0s + yy;
    LOADROW(C, y + 1)
    CONVOUT(A, B, C, y)
    LOADROW(A, y + 2)
    CONVOUT(B, C, A, y + 1)
    LOADROW(B, y + 3)
    CONVOUT(C, A, B, y + 2)
  }
#undef LOADROW
#undef CONVOUT
}

// ---------------------------------------------------------------------------
// k_kv: per 64-position tile: k-logit GEMV (lane=position, wave=head),
// exp, then kv[kc][dv] accumulation via readlane broadcast. No barriers.
// ---------------------------------------------------------------------------
__global__ __launch_bounds__(256) void k_kv(
    const float* __restrict__ x, const float* __restrict__ WkT,
    const __hip_bfloat16* __restrict__ vbuf, float* __restrict__ partials,
    int y0s, int ys, int first, int nbh)
{
  __shared__ unsigned vl[64 * 129];   // 33 KB: [n][c-pairs], stride 129 u32
  const int t = threadIdx.x;
  const int lane = t & 63;
  const int h = __builtin_amdgcn_readfirstlane(t >> 6);
  const int bid = blockIdx.x;
  const int b  = (bid >= nbh) ? 1 : 0;
  const int bh = bid - b * nbh;
  const int ntiles = ys * (NPEN / 64);

  float kvacc[32], sS[32];
#pragma unroll
  for (int j = 0; j < 32; ++j) { kvacc[j] = 0.f; sS[j] = 0.f; }

  const size_t Nsl = (size_t)ys * NPEN;
  const float* xb = x + (size_t)b * CH * NPOS + (size_t)y0s * NPEN;
  const ushort* vbu = (const ushort*)(vbuf) + (size_t)(b * CH + h * DV) * Nsl;

  for (int tile = bh; tile < ntiles; tile += nbh) {
    const int n0 = tile * 64;
    // --- phase 1: k logits (32 rows of this head) ---
    float wr[32];
#pragma unroll
    for (int j = 0; j < 32; ++j) wr[j] = 0.f;
    const float* xp = xb + n0 + lane;
#pragma unroll 8
    for (int c = 0; c < CH; ++c) {
      const float xv = xp[(size_t)c * NPOS];
      const float* wk = WkT + c * 128 + h * 32;
#pragma unroll
      for (int j = 0; j < 32; ++j) wr[j] = fmaf(wk[j], xv, wr[j]);
    }
    // --- exp (max-free: |logit| < ~3) + S partial ---
#pragma unroll
    for (int j = 0; j < 32; ++j) { wr[j] = __expf(wr[j]); sS[j] += wr[j]; }
    // --- stage own head's v (64 ch x 64 pos) transposed into LDS (u32 pairs) ---
#pragma unroll
    for (int c2 = 0; c2 < 32; ++c2) {
      const unsigned q0 = vbu[(size_t)(2 * c2)     * Nsl + n0 + lane];
      const unsigned q1 = vbu[(size_t)(2 * c2 + 1) * Nsl + n0 + lane];
      vl[lane * 129 + h * 32 + c2] = q0 | (q1 << 16);
    }
    __asm__ __volatile__("" ::: "memory");
    // --- phase 3: kv[kc][dv=lane] += wexp(kc,n) * v(dv,n) ---
    const int cp = h * 32 + (lane >> 1);
    const bool hi = (lane & 1);
    for (int n = 0; n < 64; ++n) {
      const unsigned pair = vl[n * 129 + cp];
      const float vv = __uint_as_float(hi ? (pair & 0xffff0000u)
                                          : (pair << 16));
#pragma unroll
      for (int kc = 0; kc < 32; ++kc) {
        const float w = __uint_as_float(
            (unsigned)__builtin_amdgcn_readlane((int)__float_as_uint(wr[kc]), n));
        kvacc[kc] = fmaf(w, vv, kvacc[kc]);
      }
    }
    __asm__ __volatile__("" ::: "memory");
  }

  float* pb = partials + (size_t)bid * PART_F + h * 2048;
  if (first) {
#pragma unroll
    for (int kc = 0; kc < 32; ++kc) pb[kc * 64 + lane] = kvacc[kc];
  } else {
#pragma unroll
    for (int kc = 0; kc < 32; ++kc) pb[kc * 64 + lane] += kvacc[kc];
  }
#pragma unroll
  for (int kc = 0; kc < 32; ++kc) {
    float s = sS[kc];
    s += __shfl_xor(s, 1);  s += __shfl_xor(s, 2);  s += __shfl_xor(s, 4);
    s += __shfl_xor(s, 8);  s += __shfl_xor(s, 16); s += __shfl_xor(s, 32);
    sS[kc] = s;
  }
  if (lane == 0) {
    float* ps = partials + (size_t)bid * PART_F + 8192 + h * 32;
    if (first) {
#pragma unroll
      for (int kc = 0; kc < 32; ++kc) ps[kc] = sS[kc];
    } else {
#pragma unroll
      for (int kc = 0; kc < 32; ++kc) ps[kc] += sS[kc];
    }
  }
}

// ---------------------------------------------------------------------------
// Reduction: stage A (k-split by 8, parallel over e), then S-reduce, then
// final kv reduce + normalize.
// ---------------------------------------------------------------------------
__global__ __launch_bounds__(256) void k_red_a(
    const float* __restrict__ partials, float* __restrict__ partial2, int nbh)
{
  const int bid = blockIdx.x;              // 2 * 8 * 33
  const int ech = bid % 33, kc = (bid / 33) & 7, b = bid / 264;
  const int e = ech * 256 + threadIdx.x;
  if (e >= PART_F) return;
  const int kpc = nbh / 8;
  const float* pbase = partials + (size_t)(b * nbh + kc * kpc) * PART_F + e;
  float s0 = 0.f, s1 = 0.f, s2 = 0.f, s3 = 0.f;
  for (int k = 0; k < kpc; k += 4) {
    s0 += pbase[(size_t)(k + 0) * PART_F];
    s1 += pbase[(size_t)(k + 1) * PART_F];
    s2 += pbase[(size_t)(k + 2) * PART_F];
    s3 += pbase[(size_t)(k + 3) * PART_F];
  }
  partial2[(size_t)(b * 8 + kc) * PART_F + e] = (s0 + s1) + (s2 + s3);
}

__global__ __launch_bounds__(256) void k_red_s(
    const float* __restrict__ partial2, float* __restrict__ Sfin)
{
  const int t = threadIdx.x;               // 256 = 2b x 128
  const int b = t >> 7, i = t & 127;
  float s = 0.f;
#pragma unroll
  for (int kc = 0; kc < 8; ++kc)
    s += partial2[(size_t)(b * 8 + kc) * PART_F + 8192 + i];
  Sfin[b * 128 + i] = s;
}

__global__ __launch_bounds__(256) void k_red_b(
    const float* __restrict__ partial2, const float* __restrict__ Sfin,
    float* __restrict__ kvn)
{
  const int bid = blockIdx.x;              // 64 = 2b x 32 chunks
  const int chunk = bid & 31, b = bid >> 5;
  const int e = chunk * 256 + threadIdx.x; // < 8192
  float s = 0.f;
#pragma unroll
  for (int kc = 0; kc < 8; ++kc)
    s += partial2[(size_t)(b * 8 + kc) * PART_F + e];
  kvn[(size_t)b * 8192 + e] = s / Sfin[b * 128 + (e >> 6)];
}

// ---------------------------------------------------------------------------
// k_out: q GEMV + lane-local softmax(32) + out = q_sm · kvn.
// ---------------------------------------------------------------------------
__global__ __launch_bounds__(256) void k_out(
    const float* __restrict__ x, const float* __restrict__ WqT,
    const float* __restrict__ kvn, float* __restrict__ out)
{
  const int t = threadIdx.x, lane = t & 63;
  const int h = __builtin_amdgcn_readfirstlane(t >> 6);
  const int bid = blockIdx.x;
  const int b  = bid / (NPOS / 64);
  const int n0 = (bid % (NPOS / 64)) * 64;
  const float* xb = x + (size_t)b * CH * NPOS + n0 + lane;

  float qa[32];
#pragma unroll
  for (int j = 0; j < 32; ++j) qa[j] = 0.f;
#pragma unroll 8
  for (int c = 0; c < CH; ++c) {
    const float xv = xb[(size_t)c * NPOS];
    const float* wq = WqT + c * 128 + h * 32;
#pragma unroll
    for (int j = 0; j < 32; ++j) qa[j] = fmaf(wq[j], xv, qa[j]);
  }
  float m = qa[0];
#pragma unroll
  for (int j = 1; j < 32; ++j) m = fmaxf(m, qa[j]);
  float se = 0.f;
#pragma unroll
  for (int j = 0; j < 32; ++j) { qa[j] = __expf(qa[j] - m); se += qa[j]; }
  const float sc = 1.f / (se * (1.f + 1e-6f));
#pragma unroll
  for (int j = 0; j < 32; ++j) qa[j] *= sc;

  float oa[64];
#pragma unroll
  for (int d = 0; d < 64; ++d) oa[d] = 0.f;
  const float* kvh = kvn + (size_t)(b * NHD + h) * 2048;
#pragma unroll
  for (int kc = 0; kc < 32; ++kc) {
    const float* kr = kvh + kc * 64;
#pragma unroll
    for (int d = 0; d < 64; ++d) oa[d] = fmaf(qa[kc], kr[d], oa[d]);
  }
  float* ob = out + (size_t)(b * CH + h * DV) * NPOS + n0 + lane;
#pragma unroll
  for (int d = 0; d < 64; ++d) ob[(size_t)d * NPOS] = oa[d];
}

// ---------------------------------------------------------------------------
extern "C" void kernel_launch(void* const* d_in, const int* in_sizes, int n_in,
                              void* d_out, int out_size, void* d_ws, size_t ws_size,
                              hipStream_t stream)
{
  const float* x  = (const float*)d_in[0];
  const float* Wq = (const float*)d_in[1];
  const float* Wk = (const float*)d_in[2];
  const float* Wv = (const float*)d_in[3];
  const float* bv = (const float*)d_in[4];
  float* out = (float*)d_out;
  float* ws  = (float*)d_ws;

  // ws (f32 words): WqT 32768 | WkT 32768 | kvn 16384 | Sfin 256 |
  //                 partial2 16*8320 | partials nb*8320 | vbuf (bf16)
  float* WqT      = ws;
  float* WkT      = ws + 32768;
  float* kvn      = ws + 65536;
  float* Sfin     = ws + 81920;
  float* partial2 = ws + 82176;
  float* partials = partial2 + 16 * PART_F;
  const size_t head = 82176 + 16 * PART_F;

  const size_t wsf = ws_size / 4;
  static const int cand[][2] = {
    {1024,48},{1024,24},{512,24},{1024,12},{512,12},{1024,6},
    {512,6},{512,3},{256,6},{256,3},{128,3},{64,3},{32,3}};
  int nb = 32, ys = 3;
  for (int i = 0; i < 13; ++i) {
    const size_t need = head + (size_t)cand[i][0] * PART_F
                      + (size_t)cand[i][1] * 589824;
    if (need <= wsf) { nb = cand[i][0]; ys = cand[i][1]; break; }
  }
  __hip_bfloat16* vbuf = (__hip_bfloat16*)(partials + (size_t)nb * PART_F);

  k_prep<<<128, 256, 0, stream>>>(Wq, Wk, WqT, WkT);

  const int nslab = 48 / ys;
  for (int s = 0; s < nslab; ++s) {
    k_conv<<<1152, 256, 0, stream>>>(x, Wv, bv, vbuf, s * ys, ys);
    k_kv  <<<nb,   256, 0, stream>>>(x, WkT, vbuf, partials,
                                     s * ys, ys, (s == 0) ? 1 : 0, nb / 2);
  }
  k_red_a<<<528, 256, 0, stream>>>(partials, partial2, nb / 2);
  k_red_s<<<1,   256, 0, stream>>>(partial2, Sfin);
  k_red_b<<<64,  256, 0, stream>>>(partial2, Sfin, kvn);
  k_out <<<2 * (NPOS / 64), 256, 0, stream>>>(x, WqT, kvn, out);
}

// Round 5
// 548.454 us; speedup vs baseline: 7.5208x; 1.6983x over previous
//
#include <hip/hip_runtime.h>
#include <hip/hip_bf16.h>

static constexpr int CH   = 256;
static constexpr int NHD  = 4;
static constexpr int DV   = 64;
static constexpr int SY = 48, SX = 48, SZ = 48;
static constexpr int NPEN = SY * SX;     // 2304
static constexpr int NPOS = NPEN * SZ;   // 110592
static constexpr int PF2  = 128 * 80;    // partial floats per block (kv 128x64 + S col + pad)

typedef float f32x4 __attribute__((ext_vector_type(4)));
typedef short bf8   __attribute__((ext_vector_type(8)));
union U16x4 { uint4 u; bf8 h; };

__device__ __forceinline__ ushort f2bf(float f) {
  return __bfloat16_as_ushort(__float2bfloat16(f));
}
__device__ __forceinline__ uint pk2(float lo, float hi) {
  return ((uint)f2bf(hi) << 16) | (uint)f2bf(lo);
}

// ---------------------------------------------------------------------------
// Prep: Wqk bf16 [256 rows][256 c]: rows 0..127 = Wq, 128..255 = Wk.
// ---------------------------------------------------------------------------
__global__ __launch_bounds__(256) void k_prep2(
    const float* __restrict__ Wq, const float* __restrict__ Wk,
    ushort* __restrict__ Wqk)
{
  const int i = blockIdx.x * 256 + threadIdx.x;   // grid 256 -> 65536
  const int r = i >> 8, c = i & 255;
  const float v = (r < 128) ? Wq[r * 256 + c] : Wk[(r - 128) * 256 + c];
  Wqk[i] = f2bf(v);
}

// ---------------------------------------------------------------------------
// Depthwise 3x3x3 conv + bias -> v (bf16), register-rolling window (unchanged).
// ---------------------------------------------------------------------------
__global__ __launch_bounds__(256) void k_conv(
    const float* __restrict__ x, const float* __restrict__ Wv,
    const float* __restrict__ bv, __hip_bfloat16* __restrict__ vbuf,
    int y0s, int ys)
{
  const int gid = blockIdx.x * 256 + threadIdx.x;   // 2*256*576 total
  const int zq  = gid % 12;
  const int xx  = (gid / 12) % 48;
  const int c   = (gid / 576) & 255;
  const int b   = gid / 147456;
  const int zb  = zq * 4;

  const float* xc = x + (size_t)(b * CH + c) * NPOS;
  float w[27];
  {
    const float* wv = Wv + c * 27;
#pragma unroll
    for (int j = 0; j < 27; ++j) w[j] = wv[j];
  }
  const float bias = bv[c];

  const bool zlo = (zb > 0);
  const bool zhi = (zq < 11);
  bool colok[3];
  int  coloff[3];
#pragma unroll
  for (int dx = 0; dx < 3; ++dx) {
    const int xcol = xx - 1 + dx;
    colok[dx]  = (xcol >= 0) && (xcol < SX);
    coloff[dx] = xcol * SZ + zb;
  }

  float A[18], B[18], C[18];

#define LOADROW(R, yy_)                                                        \
  {                                                                            \
    const int y_ = (yy_);                                                      \
    const bool yok_ = (y_ >= 0) && (y_ < SY);                                  \
    const float* rowp_ = xc + (size_t)y_ * NPEN;                               \
    _Pragma("unroll")                                                          \
    for (int dx = 0; dx < 3; ++dx) {                                           \
      float m0, m1, m2, m3, zm, zp;                                            \
      if (yok_ && colok[dx]) {                                                 \
        const float* bp_ = rowp_ + coloff[dx];                                 \
        const float4 m_ = *(const float4*)bp_;                                 \
        m0 = m_.x; m1 = m_.y; m2 = m_.z; m3 = m_.w;                            \
        zm = zlo ? bp_[-1] : 0.f;                                              \
        zp = zhi ? bp_[4]  : 0.f;                                              \
      } else { m0 = m1 = m2 = m3 = 0.f; zm = 0.f; zp = 0.f; }                  \
      R[dx*6+0] = zm; R[dx*6+1] = m0; R[dx*6+2] = m1;                          \
      R[dx*6+3] = m2; R[dx*6+4] = m3; R[dx*6+5] = zp;                          \
    }                                                                          \
  }

#define CONVOUT(R0, R1, R2, yy_)                                               \
  {                                                                            \
    float a0 = bias, a1 = bias, a2 = bias, a3 = bias;                          \
    _Pragma("unroll")                                                          \
    for (int kx = 0; kx < 3; ++kx) {                                           \
      _Pragma("unroll")                                                        \
      for (int kz = 0; kz < 3; ++kz) {                                         \
        const float w0_ = w[(0*3+kx)*3+kz];                                    \
        const float w1_ = w[(1*3+kx)*3+kz];                                    \
        const float w2_ = w[(2*3+kx)*3+kz];                                    \
        a0 = fmaf(w0_, R0[kx*6+kz+0], a0); a0 = fmaf(w1_, R1[kx*6+kz+0], a0);  \
        a0 = fmaf(w2_, R2[kx*6+kz+0], a0);                                     \
        a1 = fmaf(w0_, R0[kx*6+kz+1], a1); a1 = fmaf(w1_, R1[kx*6+kz+1], a1);  \
        a1 = fmaf(w2_, R2[kx*6+kz+1], a1);                                     \
        a2 = fmaf(w0_, R0[kx*6+kz+2], a2); a2 = fmaf(w1_, R1[kx*6+kz+2], a2);  \
        a2 = fmaf(w2_, R2[kx*6+kz+2], a2);                                     \
        a3 = fmaf(w0_, R0[kx*6+kz+3], a3); a3 = fmaf(w1_, R1[kx*6+kz+3], a3);  \
        a3 = fmaf(w2_, R2[kx*6+kz+3], a3);                                     \
      }                                                                        \
    }                                                                          \
    const size_t o_ = (size_t)(b * CH + c) * ((size_t)ys * NPEN) +             \
                      (size_t)((yy_) - y0s) * NPEN + xx * SZ + zb;             \
    union { unsigned u[2]; } pk_;                                              \
    pk_.u[0] = (((unsigned)__bfloat16_as_ushort(__float2bfloat16(a1))) << 16)  \
             | (unsigned)__bfloat16_as_ushort(__float2bfloat16(a0));           \
    pk_.u[1] = (((unsigned)__bfloat16_as_ushort(__float2bfloat16(a3))) << 16)  \
             | (unsigned)__bfloat16_as_ushort(__float2bfloat16(a2));           \
    *(uint2*)&vbuf[o_] = *(const uint2*)pk_.u;                                 \
  }

  LOADROW(A, y0s - 1)
  LOADROW(B, y0s)
  for (int yy = 0; yy < ys; yy += 3) {
    const int y = y0s + yy;
    LOADROW(C, y + 1)
    CONVOUT(A, B, C, y)
    LOADROW(A, y + 2)
    CONVOUT(B, C, A, y + 1)
    LOADROW(B, y + 3)
    CONVOUT(C, A, B, y + 2)
  }
#undef LOADROW
#undef CONVOUT
}

// ---------------------------------------------------------------------------
// k_pass1 (MFMA): per 64-n tile: GEMM1 logits (Wqk 256x256 x x-tile 256x64),
// q: softmax -> qsm bf16 [n][128]; k: exp -> LDS -> GEMM2 kv += wexp * v^T
// (+ ones-column for S). C2 accumulates in registers across tiles.
// ---------------------------------------------------------------------------
__global__ __launch_bounds__(256) void k_pass1(
    const float* __restrict__ x, const ushort* __restrict__ Wqk,
    const ushort* __restrict__ vbuf, uint* __restrict__ qsm,
    float* __restrict__ partials, int y0s, int ys, int first, int nbh)
{
  __shared__ uint4  ldsx[64 * 33];    // x-tile bf16 [n][32 swz 16B-chunks + pad]
  __shared__ ushort ldsw[128 * 72];   // wexp bf16 [kc-row][n], stride 72
  uint* ldsq = (uint*)ldsx;           // aliased (barrier-separated): [n][68]

  const int t    = threadIdx.x;
  const int lane = t & 63;
  const int w    = __builtin_amdgcn_readfirstlane(t >> 6);
  const int bid  = blockIdx.x;
  const int b    = (bid >= nbh) ? 1 : 0;
  const int bh   = bid - b * nbh;
  const int ntiles = ys * 36;
  const size_t Nsl = (size_t)ys * NPEN;

  const int l15 = lane & 15;
  const int lg  = lane >> 4;

  const int sn   = t & 63;            // staging: n row
  const int sc0  = (t >> 6) * 64;     // staging: channel base
  const int snx  = sn & 7;
  const int swzb = sn * 33;

  bf8 Bones;
  {
    const short o = (l15 == 0) ? (short)0x3F80 : (short)0;
#pragma unroll
    for (int j = 0; j < 8; ++j) Bones[j] = o;
  }

  f32x4 C2[2][5];
#pragma unroll
  for (int i = 0; i < 2; ++i)
#pragma unroll
    for (int j = 0; j < 5; ++j) C2[i][j] = (f32x4){0.f, 0.f, 0.f, 0.f};

  const float*  xbase = x + (size_t)b * CH * NPOS + (size_t)y0s * NPEN;
  const ushort* wq    = Wqk + (size_t)(w * 64) * 256;
  const ushort* vb    = vbuf + (size_t)(b * CH + w * 64) * Nsl;

  for (int tile = bh; tile < ntiles; tile += nbh) {
    const int nloc0 = tile * 64;
    // ---- phase A: stage x-tile -> LDS bf16 [n][c], swizzled ----
    {
      const float* xp = xbase + nloc0 + sn;
#pragma unroll
      for (int ci = 0; ci < 8; ++ci) {
        float f[8];
#pragma unroll
        for (int j = 0; j < 8; ++j)
          f[j] = xp[(size_t)(sc0 + ci * 8 + j) * NPOS];
        uint4 pk;
        pk.x = pk2(f[0], f[1]); pk.y = pk2(f[2], f[3]);
        pk.z = pk2(f[4], f[5]); pk.w = pk2(f[6], f[7]);
        ldsx[swzb + (((sc0 >> 3) + ci) ^ snx)] = pk;
      }
    }
    __syncthreads();
    // ---- phase B: GEMM1: C1[64 W-rows (this wave)][64 n] ----
    f32x4 C1[4][4];
#pragma unroll
    for (int rt = 0; rt < 4; ++rt)
#pragma unroll
      for (int ct = 0; ct < 4; ++ct) C1[rt][ct] = (f32x4){0.f, 0.f, 0.f, 0.f};
#pragma unroll
    for (int ks = 0; ks < 8; ++ks) {
      const int kb = ks * 32 + lg * 8;
      bf8 A[4], Bf[4];
#pragma unroll
      for (int rt = 0; rt < 4; ++rt)
        A[rt] = *(const bf8*)&wq[(size_t)(rt * 16 + l15) * 256 + kb];
#pragma unroll
      for (int ct = 0; ct < 4; ++ct) {
        const int n = ct * 16 + l15;
        U16x4 u; u.u = ldsx[n * 33 + ((kb >> 3) ^ (n & 7))];
        Bf[ct] = u.h;
      }
#pragma unroll
      for (int rt = 0; rt < 4; ++rt)
#pragma unroll
        for (int ct = 0; ct < 4; ++ct)
          C1[rt][ct] = __builtin_amdgcn_mfma_f32_16x16x32_bf16(
              A[rt], Bf[ct], C1[rt][ct], 0, 0, 0);
    }
    __syncthreads();   // C1 done; ldsx reusable as ldsq
    // ---- phase C: q-waves softmax -> ldsq ; k-waves exp -> ldsw ----
    if (w >= 2) {
      const int kcb = (w - 2) * 64;
#pragma unroll
      for (int rt = 0; rt < 4; ++rt)
#pragma unroll
        for (int ct = 0; ct < 4; ++ct) {
          const int n = ct * 16 + l15;
          ushort* wr = &ldsw[(size_t)(kcb + rt * 16 + lg * 4) * 72 + n];
#pragma unroll
          for (int r = 0; r < 4; ++r)
            wr[r * 72] = f2bf(__expf(C1[rt][ct][r]));
        }
    } else {
#pragma unroll
      for (int ct = 0; ct < 4; ++ct) {
        const int n = ct * 16 + l15;
#pragma unroll
        for (int p = 0; p < 2; ++p) {
          float m = -1e30f;
#pragma unroll
          for (int ri = 0; ri < 2; ++ri)
#pragma unroll
            for (int r = 0; r < 4; ++r) m = fmaxf(m, C1[2*p+ri][ct][r]);
          m = fmaxf(m, __shfl_xor(m, 16));
          m = fmaxf(m, __shfl_xor(m, 32));
          float e[2][4]; float s = 0.f;
#pragma unroll
          for (int ri = 0; ri < 2; ++ri)
#pragma unroll
            for (int r = 0; r < 4; ++r) {
              e[ri][r] = __expf(C1[2*p+ri][ct][r] - m); s += e[ri][r];
            }
          s += __shfl_xor(s, 16); s += __shfl_xor(s, 32);
          const float inv = 1.f / s;
#pragma unroll
          for (int ri = 0; ri < 2; ++ri) {
            const int rt = 2 * p + ri;
            const uint idx = n * 68 + w * 32 + rt * 8 + lg * 2;
            ldsq[idx]     = pk2(e[ri][0] * inv, e[ri][1] * inv);
            ldsq[idx + 1] = pk2(e[ri][2] * inv, e[ri][3] * inv);
          }
        }
      }
    }
    __syncthreads();   // ldsw + ldsq ready
    // ---- phase E: GEMM2 (head w): C2[32 kc][64 dv + S] += wexp * v^T ----
#pragma unroll
    for (int ks = 0; ks < 2; ++ks) {
      const int kb = ks * 32 + lg * 8;
      bf8 A2[2], Bv[4];
#pragma unroll
      for (int rt2 = 0; rt2 < 2; ++rt2)
        A2[rt2] = *(const bf8*)&ldsw[(size_t)(w * 32 + rt2 * 16 + l15) * 72 + kb];
#pragma unroll
      for (int ct = 0; ct < 4; ++ct)
        Bv[ct] = *(const bf8*)&vb[(size_t)(ct * 16 + l15) * Nsl + nloc0 + kb];
#pragma unroll
      for (int rt2 = 0; rt2 < 2; ++rt2) {
#pragma unroll
        for (int ct = 0; ct < 4; ++ct)
          C2[rt2][ct] = __builtin_amdgcn_mfma_f32_16x16x32_bf16(
              A2[rt2], Bv[ct], C2[rt2][ct], 0, 0, 0);
        C2[rt2][4] = __builtin_amdgcn_mfma_f32_16x16x32_bf16(
            A2[rt2], Bones, C2[rt2][4], 0, 0, 0);
      }
    }
    // ---- phase F: stream qsm tile to global (coalesced) ----
    {
      uint* qg = qsm + ((size_t)b * NPOS + (size_t)y0s * NPEN + nloc0) * 64;
      for (int i = t; i < 4096; i += 256)
        qg[i] = ldsq[(i >> 6) * 68 + (i & 63)];
    }
    __syncthreads();   // all LDS reads done before next tile's staging
  }

  // ---- write / RMW partials: [kc-row 128][80] ----
  float* pb = partials + (size_t)bid * PF2;
#pragma unroll
  for (int rt2 = 0; rt2 < 2; ++rt2)
#pragma unroll
    for (int ct = 0; ct < 5; ++ct)
#pragma unroll
      for (int r = 0; r < 4; ++r) {
        const int row = w * 32 + rt2 * 16 + lg * 4 + r;
        const int col = ct * 16 + l15;
        const int idx = row * 80 + col;
        if (first) pb[idx] = C2[rt2][ct][r];
        else       pb[idx] += C2[rt2][ct][r];
      }
}

// ---------------------------------------------------------------------------
// Reductions over pass-1 block partials.
// ---------------------------------------------------------------------------
__global__ __launch_bounds__(256) void k_red_a(
    const float* __restrict__ partials, float* __restrict__ partial2, int nbh)
{
  const int bid = blockIdx.x;               // 2 * 8 * 40
  const int ec  = bid % 40, kc = (bid / 40) & 7, b = bid / 320;
  const int e   = ec * 256 + threadIdx.x;
  if (e >= PF2) return;
  const int kpc = nbh / 8;
  const float* pbase = partials + (size_t)(b * nbh + kc * kpc) * PF2 + e;
  float s0 = 0.f, s1 = 0.f, s2 = 0.f, s3 = 0.f;
  for (int k = 0; k < kpc; k += 4) {
    s0 += pbase[(size_t)(k + 0) * PF2];
    s1 += pbase[(size_t)(k + 1) * PF2];
    s2 += pbase[(size_t)(k + 2) * PF2];
    s3 += pbase[(size_t)(k + 3) * PF2];
  }
  partial2[(size_t)(b * 8 + kc) * PF2 + e] = (s0 + s1) + (s2 + s3);
}

__global__ __launch_bounds__(256) void k_red_s(
    const float* __restrict__ partial2, float* __restrict__ Sfin)
{
  const int t = threadIdx.x;                // 256 = 2b x 128 kc
  const int b = t >> 7, kc = t & 127;
  float s = 0.f;
#pragma unroll
  for (int j = 0; j < 8; ++j)
    s += partial2[(size_t)(b * 8 + j) * PF2 + kc * 80 + 64];
  Sfin[b * 128 + kc] = s;
}

__global__ __launch_bounds__(256) void k_red_b(
    const float* __restrict__ partial2, const float* __restrict__ Sfin,
    float* __restrict__ kvn)
{
  const int bid = blockIdx.x;               // 64 = 2b x 32
  const int chunk = bid & 31, b = bid >> 5;
  const int e = chunk * 256 + threadIdx.x;  // < 8192
  const int kc = e >> 6, dv = e & 63;
  float s = 0.f;
#pragma unroll
  for (int j = 0; j < 8; ++j)
    s += partial2[(size_t)(b * 8 + j) * PF2 + kc * 80 + dv];
  kvn[(size_t)b * 8192 + e] = s / (Sfin[b * 128 + kc] * (1.f + 1e-6f));
}

// ---------------------------------------------------------------------------
// k_out2: out[n][c] = qsm[n][.] · kvn ; lane = n, wave = head.
// ---------------------------------------------------------------------------
__global__ __launch_bounds__(256) void k_out2(
    const uint* __restrict__ qsm, const float* __restrict__ kvn,
    float* __restrict__ out)
{
  const int t = threadIdx.x, lane = t & 63;
  const int w = __builtin_amdgcn_readfirstlane(t >> 6);
  const int bid = blockIdx.x;
  const int b  = bid / 1728;
  const int n0 = (bid % 1728) * 64;

  const uint* qp = qsm + ((size_t)b * NPOS + n0 + lane) * 64 + w * 16;
  uint q[16];
  *(uint4*)&q[0]  = *(const uint4*)(qp);
  *(uint4*)&q[4]  = *(const uint4*)(qp + 4);
  *(uint4*)&q[8]  = *(const uint4*)(qp + 8);
  *(uint4*)&q[12] = *(const uint4*)(qp + 12);
  float qa[32];
#pragma unroll
  for (int j = 0; j < 16; ++j) {
    qa[2 * j]     = __uint_as_float(q[j] << 16);
    qa[2 * j + 1] = __uint_as_float(q[j] & 0xFFFF0000u);
  }

  float oa[64];
#pragma unroll
  for (int d = 0; d < 64; ++d) oa[d] = 0.f;
  const float* kvh = kvn + (size_t)b * 8192 + (size_t)(w * 32) * 64;
#pragma unroll
  for (int kc = 0; kc < 32; ++kc) {
    const float* kr = kvh + kc * 64;
#pragma unroll
    for (int d = 0; d < 64; ++d) oa[d] = fmaf(qa[kc], kr[d], oa[d]);
  }
  float* ob = out + (size_t)(b * CH + w * DV) * NPOS + n0 + lane;
#pragma unroll
  for (int d = 0; d < 64; ++d) ob[(size_t)d * NPOS] = oa[d];
}

// ---------------------------------------------------------------------------
extern "C" void kernel_launch(void* const* d_in, const int* in_sizes, int n_in,
                              void* d_out, int out_size, void* d_ws, size_t ws_size,
                              hipStream_t stream)
{
  const float* x  = (const float*)d_in[0];
  const float* Wq = (const float*)d_in[1];
  const float* Wk = (const float*)d_in[2];
  const float* Wv = (const float*)d_in[3];
  const float* bv = (const float*)d_in[4];
  float* out = (float*)d_out;
  float* ws  = (float*)d_ws;

  // ws (u32 words): Wqk 32768 | qsm 14155776 | kvn 16384 | Sfin 256 |
  //                 partial2 16*PF2 | partials 2*nbh*PF2 | vbuf bf16
  ushort* Wqk     = (ushort*)ws;
  uint*   qsm     = (uint*)(ws + 32768);
  float*  kvn     = ws + 32768 + 14155776;
  float*  Sfin    = kvn + 16384;
  float*  partial2= Sfin + 256;
  float*  partials= partial2 + 16 * PF2;
  const size_t head = 32768 + 14155776 + 16384 + 256 + (size_t)16 * PF2;

  const size_t wsf = ws_size / 4;
  static const int cand[][2] = {
    {256,48},{256,24},{256,12},{128,12},{128,6},{64,6},{64,3},{32,3}};
  int nbh = 32, ys = 3;
  for (int i = 0; i < 8; ++i) {
    const size_t need = head + (size_t)(2 * cand[i][0]) * PF2
                      + (size_t)cand[i][1] * 589824;
    if (need <= wsf) { nbh = cand[i][0]; ys = cand[i][1]; break; }
  }
  __hip_bfloat16* vbuf = (__hip_bfloat16*)(partials + (size_t)(2 * nbh) * PF2);

  k_prep2<<<256, 256, 0, stream>>>(Wq, Wk, Wqk);

  const int nslab = 48 / ys;
  for (int s = 0; s < nslab; ++s) {
    k_conv <<<1152,    256, 0, stream>>>(x, Wv, bv, vbuf, s * ys, ys);
    k_pass1<<<2 * nbh, 256, 0, stream>>>(x, Wqk, (const ushort*)vbuf, qsm,
                                         partials, s * ys, ys,
                                         (s == 0) ? 1 : 0, nbh);
  }
  k_red_a<<<640, 256, 0, stream>>>(partials, partial2, nbh);
  k_red_s<<<1,   256, 0, stream>>>(partial2, Sfin);
  k_red_b<<<64,  256, 0, stream>>>(partial2, Sfin, kvn);
  k_out2 <<<2 * 1728, 256, 0, stream>>>(qsm, kvn, out);
}

// Round 6
// 468.574 us; speedup vs baseline: 8.8029x; 1.1705x over previous
//
#include <hip/hip_runtime.h>
#include <hip/hip_bf16.h>

static constexpr int CH   = 256;
static constexpr int NHD  = 4;
static constexpr int DV   = 64;
static constexpr int SY = 48, SX = 48, SZ = 48;
static constexpr int NPEN = SY * SX;     // 2304
static constexpr int NPOS = NPEN * SZ;   // 110592
static constexpr int PF2  = 128 * 80;    // kv partial floats per block

typedef float f32x4 __attribute__((ext_vector_type(4)));
typedef short bf8   __attribute__((ext_vector_type(8)));
union U16x4 { uint4 u; bf8 h; };

__device__ __forceinline__ ushort f2bf(float f) {
  return __bfloat16_as_ushort(__float2bfloat16(f));
}
__device__ __forceinline__ uint pk2(float lo, float hi) {
  return ((uint)f2bf(hi) << 16) | (uint)f2bf(lo);
}

// ---------------------------------------------------------------------------
// Prep: Wqk2 bf16 [256 rows][256 c], per-head blocks:
// row' = h*64 + j      <- Wq row h*32+j
// row' = h*64 + 32 + j <- Wk row h*32+j
// ---------------------------------------------------------------------------
__global__ __launch_bounds__(256) void k_prep2(
    const float* __restrict__ Wq, const float* __restrict__ Wk,
    ushort* __restrict__ Wqk2)
{
  const int i = blockIdx.x * 256 + threadIdx.x;   // grid 256 -> 65536
  const int rp = i >> 8, c = i & 255;
  const int h = rp >> 6, s = (rp >> 5) & 1, j = rp & 31;
  const float v = s ? Wk[(h * 32 + j) * 256 + c] : Wq[(h * 32 + j) * 256 + c];
  Wqk2[i] = f2bf(v);
}

// ---------------------------------------------------------------------------
// Depthwise 3x3x3 conv + bias -> v (bf16), register-rolling window (unchanged).
// ---------------------------------------------------------------------------
__global__ __launch_bounds__(256) void k_conv(
    const float* __restrict__ x, const float* __restrict__ Wv,
    const float* __restrict__ bv, __hip_bfloat16* __restrict__ vbuf,
    int y0s, int ys)
{
  const int gid = blockIdx.x * 256 + threadIdx.x;   // 2*256*576 total
  const int zq  = gid % 12;
  const int xx  = (gid / 12) % 48;
  const int c   = (gid / 576) & 255;
  const int b   = gid / 147456;
  const int zb  = zq * 4;

  const float* xc = x + (size_t)(b * CH + c) * NPOS;
  float w[27];
  {
    const float* wv = Wv + c * 27;
#pragma unroll
    for (int j = 0; j < 27; ++j) w[j] = wv[j];
  }
  const float bias = bv[c];

  const bool zlo = (zb > 0);
  const bool zhi = (zq < 11);
  bool colok[3];
  int  coloff[3];
#pragma unroll
  for (int dx = 0; dx < 3; ++dx) {
    const int xcol = xx - 1 + dx;
    colok[dx]  = (xcol >= 0) && (xcol < SX);
    coloff[dx] = xcol * SZ + zb;
  }

  float A[18], B[18], C[18];

#define LOADROW(R, yy_)                                                        \
  {                                                                            \
    const int y_ = (yy_);                                                      \
    const bool yok_ = (y_ >= 0) && (y_ < SY);                                  \
    const float* rowp_ = xc + (size_t)y_ * NPEN;                               \
    _Pragma("unroll")                                                          \
    for (int dx = 0; dx < 3; ++dx) {                                           \
      float m0, m1, m2, m3, zm, zp;                                            \
      if (yok_ && colok[dx]) {                                                 \
        const float* bp_ = rowp_ + coloff[dx];                                 \
        const float4 m_ = *(const float4*)bp_;                                 \
        m0 = m_.x; m1 = m_.y; m2 = m_.z; m3 = m_.w;                            \
        zm = zlo ? bp_[-1] : 0.f;                                              \
        zp = zhi ? bp_[4]  : 0.f;                                              \
      } else { m0 = m1 = m2 = m3 = 0.f; zm = 0.f; zp = 0.f; }                  \
      R[dx*6+0] = zm; R[dx*6+1] = m0; R[dx*6+2] = m1;                          \
      R[dx*6+3] = m2; R[dx*6+4] = m3; R[dx*6+5] = zp;                          \
    }                                                                          \
  }

#define CONVOUT(R0, R1, R2, yy_)                                               \
  {                                                                            \
    float a0 = bias, a1 = bias, a2 = bias, a3 = bias;                          \
    _Pragma("unroll")                                                          \
    for (int kx = 0; kx < 3; ++kx) {                                           \
      _Pragma("unroll")                                                        \
      for (int kz = 0; kz < 3; ++kz) {                                         \
        const float w0_ = w[(0*3+kx)*3+kz];                                    \
        const float w1_ = w[(1*3+kx)*3+kz];                                    \
        const float w2_ = w[(2*3+kx)*3+kz];                                    \
        a0 = fmaf(w0_, R0[kx*6+kz+0], a0); a0 = fmaf(w1_, R1[kx*6+kz+0], a0);  \
        a0 = fmaf(w2_, R2[kx*6+kz+0], a0);                                     \
        a1 = fmaf(w0_, R0[kx*6+kz+1], a1); a1 = fmaf(w1_, R1[kx*6+kz+1], a1);  \
        a1 = fmaf(w2_, R2[kx*6+kz+1], a1);                                     \
        a2 = fmaf(w0_, R0[kx*6+kz+2], a2); a2 = fmaf(w1_, R1[kx*6+kz+2], a2);  \
        a2 = fmaf(w2_, R2[kx*6+kz+2], a2);                                     \
        a3 = fmaf(w0_, R0[kx*6+kz+3], a3); a3 = fmaf(w1_, R1[kx*6+kz+3], a3);  \
        a3 = fmaf(w2_, R2[kx*6+kz+3], a3);                                     \
      }                                                                        \
    }                                                                          \
    const size_t o_ = (size_t)(b * CH + c) * ((size_t)ys * NPEN) +             \
                      (size_t)((yy_) - y0s) * NPEN + xx * SZ + zb;             \
    union { unsigned u[2]; } pk_;                                              \
    pk_.u[0] = (((unsigned)__bfloat16_as_ushort(__float2bfloat16(a1))) << 16)  \
             | (unsigned)__bfloat16_as_ushort(__float2bfloat16(a0));           \
    pk_.u[1] = (((unsigned)__bfloat16_as_ushort(__float2bfloat16(a3))) << 16)  \
             | (unsigned)__bfloat16_as_ushort(__float2bfloat16(a2));           \
    *(uint2*)&vbuf[o_] = *(const uint2*)pk_.u;                                 \
  }

  LOADROW(A, y0s - 1)
  LOADROW(B, y0s)
  for (int yy = 0; yy < ys; yy += 3) {
    const int y = y0s + yy;
    LOADROW(C, y + 1)
    CONVOUT(A, B, C, y)
    LOADROW(A, y + 2)
    CONVOUT(B, C, A, y + 1)
    LOADROW(B, y + 3)
    CONVOUT(C, A, B, y + 2)
  }
#undef LOADROW
#undef CONVOUT
}

// ---------------------------------------------------------------------------
// k_fuse: 512 thr, 8 waves. wave w -> head h=w>>1, n-half nh=w&1.
// Per 64-n tile: async gload_lds x f32 [c][64n]; GEMM1 logits (per-head rows);
// q: softmax -> direct global qsm stores; k: exp -> per-wave LDS scratch ->
// GEMM2 kv += wexp * v^T (+ ones col for S). 2 barriers/tile.
// ---------------------------------------------------------------------------
__global__ __launch_bounds__(512) void k_fuse(
    const float* __restrict__ x, const ushort* __restrict__ Wqk2,
    const ushort* __restrict__ vbuf, uint* __restrict__ qsm,
    float* __restrict__ partials, int y0s, int ys, int first, int nbh)
{
  __shared__ float xf[CH * 64];         // [c][64n] f32, 64 KB
  __shared__ short scr[8 * 32 * 40];    // per-wave wexp [kc][40] (80B rows)

  const int t    = threadIdx.x;
  const int lane = t & 63;
  const int w    = __builtin_amdgcn_readfirstlane(t >> 6);
  const int h    = w >> 1, nh = w & 1;
  const int l15  = lane & 15, lg = lane >> 4;
  const int bid  = blockIdx.x;
  const int b    = (bid >= nbh) ? 1 : 0;
  const int bh   = bid - b * nbh;
  const int ntiles = ys * 36;
  const size_t Nsl = (size_t)ys * NPEN;

  const float*  xb = x + (size_t)b * CH * NPOS + (size_t)y0s * NPEN;
  const ushort* vb = vbuf + (size_t)(b * CH + h * 64) * Nsl;
  short* myscr = &scr[w * 32 * 40];
  const int gn_base = y0s * NPEN + nh * 32 + l15;   // + tile*64 + ct*16 -> global n

  bf8 Bones;
  {
    const short o = (l15 == 0) ? (short)0x3F80 : (short)0;
#pragma unroll
    for (int j = 0; j < 8; ++j) Bones[j] = o;
  }

  f32x4 C2[2][5];
#pragma unroll
  for (int i = 0; i < 2; ++i)
#pragma unroll
    for (int j = 0; j < 5; ++j) C2[i][j] = (f32x4){0.f, 0.f, 0.f, 0.f};

#define STAGE(tile_)                                                           \
  {                                                                            \
    const int n0_ = (tile_) * 64;                                              \
    _Pragma("unroll")                                                          \
    for (int j_ = 0; j_ < 8; ++j_) {                                           \
      const int k_ = j_ * 512 + t;            /* 16B chunk id, 0..4095 */      \
      const int c_ = k_ >> 4, nq_ = (k_ & 15) << 2;                            \
      const float* src_ = xb + (size_t)c_ * NPOS + n0_ + nq_;                  \
      __builtin_amdgcn_global_load_lds(                                        \
          (const __attribute__((address_space(1))) void*)src_,                 \
          (__attribute__((address_space(3))) void*)((char*)xf +                \
              (j_ * 512 + w * 64) * 16),                                       \
          16, 0, 0);                                                           \
    }                                                                          \
  }

  if (bh < ntiles) STAGE(bh)

  for (int tile = bh; tile < ntiles; tile += nbh) {
    const int n0 = tile * 64;
    __syncthreads();                       // xf(tile) ready (vmcnt drain)

    // ---- v prefetch for GEMM2 (used after barrier B) ----
    uint4 vr[4];
#pragma unroll
    for (int ct = 0; ct < 4; ++ct)
      vr[ct] = *(const uint4*)&vb[(size_t)(ct * 16 + l15) * Nsl +
                                  n0 + nh * 32 + lg * 8];

    // ---- GEMM1: C1[4 rt][2 ct] = Wqk2(head h rows) x xf ----
    f32x4 C1[4][2];
#pragma unroll
    for (int rt = 0; rt < 4; ++rt)
#pragma unroll
      for (int ct = 0; ct < 2; ++ct) C1[rt][ct] = (f32x4){0.f, 0.f, 0.f, 0.f};

#pragma unroll
    for (int ks = 0; ks < 8; ++ks) {
      const int c0 = ks * 32 + lg * 8;
      U16x4 a[4];
#pragma unroll
      for (int rt = 0; rt < 4; ++rt)
        a[rt].u = *(const uint4*)&Wqk2[(size_t)(h * 64 + rt * 16 + l15) * 256 + c0];
      bf8 Bf[2];
#pragma unroll
      for (int ct = 0; ct < 2; ++ct) {
        const int n = nh * 32 + ct * 16 + l15;
        float f[8];
#pragma unroll
        for (int j = 0; j < 8; ++j) f[j] = xf[(c0 + j) * 64 + n];
#pragma unroll
        for (int j = 0; j < 8; ++j) Bf[ct][j] = (short)f2bf(f[j]);
      }
#pragma unroll
      for (int rt = 0; rt < 4; ++rt)
#pragma unroll
        for (int ct = 0; ct < 2; ++ct)
          C1[rt][ct] = __builtin_amdgcn_mfma_f32_16x16x32_bf16(
              a[rt].h, Bf[ct], C1[rt][ct], 0, 0, 0);
    }

    // ---- q softmax (rt 0,1) -> direct global qsm stores ----
#pragma unroll
    for (int ct = 0; ct < 2; ++ct) {
      float m = -1e30f;
#pragma unroll
      for (int rt = 0; rt < 2; ++rt)
#pragma unroll
        for (int r = 0; r < 4; ++r) m = fmaxf(m, C1[rt][ct][r]);
      m = fmaxf(m, __shfl_xor(m, 16));
      m = fmaxf(m, __shfl_xor(m, 32));
      float e[2][4], s = 0.f;
#pragma unroll
      for (int rt = 0; rt < 2; ++rt)
#pragma unroll
        for (int r = 0; r < 4; ++r) { e[rt][r] = __expf(C1[rt][ct][r] - m); s += e[rt][r]; }
      s += __shfl_xor(s, 16);
      s += __shfl_xor(s, 32);
      const float inv = 1.f / s;
      const size_t gn = (size_t)b * NPOS + gn_base + n0 + ct * 16;
#pragma unroll
      for (int rt = 0; rt < 2; ++rt) {
        uint2 o;
        o.x = pk2(e[rt][0] * inv, e[rt][1] * inv);
        o.y = pk2(e[rt][2] * inv, e[rt][3] * inv);
        *(uint2*)&qsm[gn * 64 + h * 16 + rt * 8 + lg * 2] = o;
      }
    }

    // ---- k exp (rt 2,3) -> per-wave scratch (bf16, transposed layout) ----
#pragma unroll
    for (int rt2 = 0; rt2 < 2; ++rt2)
#pragma unroll
      for (int ct = 0; ct < 2; ++ct) {
        const int nl = ct * 16 + l15;
#pragma unroll
        for (int r = 0; r < 4; ++r)
          myscr[(rt2 * 16 + lg * 4 + r) * 40 + nl] =
              (short)f2bf(__expf(C1[rt2 + 2][ct][r]));
      }

    __syncthreads();                       // all waves done reading xf
    if (tile + nbh < ntiles) STAGE(tile + nbh)   // overwrite xf async

    // ---- GEMM2: C2[kc 32][dv 64 + S] += wexp * v^T ----
    __asm__ __volatile__("" ::: "memory");
    bf8 A2[2];
#pragma unroll
    for (int rt2 = 0; rt2 < 2; ++rt2)
      A2[rt2] = *(const bf8*)&myscr[(rt2 * 16 + l15) * 40 + lg * 8];
#pragma unroll
    for (int rt2 = 0; rt2 < 2; ++rt2) {
#pragma unroll
      for (int ct = 0; ct < 4; ++ct) {
        U16x4 v_; v_.u = vr[ct];
        C2[rt2][ct] = __builtin_amdgcn_mfma_f32_16x16x32_bf16(
            A2[rt2], v_.h, C2[rt2][ct], 0, 0, 0);
      }
      C2[rt2][4] = __builtin_amdgcn_mfma_f32_16x16x32_bf16(
          A2[rt2], Bones, C2[rt2][4], 0, 0, 0);
    }
  }
#undef STAGE

  // ---- epilogue: combine n-half pairs via LDS, RMW partials ----
  __syncthreads();
  float* comb = (float*)xf;
  if (nh == 1) {
    float* dst = comb + (h * 64 + lane) * 40;
#pragma unroll
    for (int rt2 = 0; rt2 < 2; ++rt2)
#pragma unroll
      for (int ct = 0; ct < 5; ++ct)
#pragma unroll
        for (int r = 0; r < 4; ++r)
          dst[rt2 * 20 + ct * 4 + r] = C2[rt2][ct][r];
  }
  __syncthreads();
  if (nh == 0) {
    const float* srcp = comb + (h * 64 + lane) * 40;
    float* pb = partials + (size_t)bid * PF2;
#pragma unroll
    for (int rt2 = 0; rt2 < 2; ++rt2)
#pragma unroll
      for (int ct = 0; ct < 5; ++ct)
#pragma unroll
        for (int r = 0; r < 4; ++r) {
          const float v2 = C2[rt2][ct][r] + srcp[rt2 * 20 + ct * 4 + r];
          const int row = h * 32 + rt2 * 16 + lg * 4 + r;
          const int col = ct * 16 + l15;   // ct==4 -> S col block (only l15==0 read)
          const int idx = row * 80 + col;
          if (first) pb[idx] = v2;
          else       pb[idx] += v2;
        }
  }
}

// ---------------------------------------------------------------------------
// Reductions over pass-1 block partials (unchanged).
// ---------------------------------------------------------------------------
__global__ __launch_bounds__(256) void k_red_a(
    const float* __restrict__ partials, float* __restrict__ partial2, int nbh)
{
  const int bid = blockIdx.x;               // 2 * 8 * 40
  const int ec  = bid % 40, kc = (bid / 40) & 7, b = bid / 320;
  const int e   = ec * 256 + threadIdx.x;
  if (e >= PF2) return;
  const int kpc = nbh / 8;
  const float* pbase = partials + (size_t)(b * nbh + kc * kpc) * PF2 + e;
  float s0 = 0.f, s1 = 0.f, s2 = 0.f, s3 = 0.f;
  for (int k = 0; k < kpc; k += 4) {
    s0 += pbase[(size_t)(k + 0) * PF2];
    s1 += pbase[(size_t)(k + 1) * PF2];
    s2 += pbase[(size_t)(k + 2) * PF2];
    s3 += pbase[(size_t)(k + 3) * PF2];
  }
  partial2[(size_t)(b * 8 + kc) * PF2 + e] = (s0 + s1) + (s2 + s3);
}

__global__ __launch_bounds__(256) void k_red_s(
    const float* __restrict__ partial2, float* __restrict__ Sfin)
{
  const int t = threadIdx.x;                // 256 = 2b x 128 kc
  const int b = t >> 7, kc = t & 127;
  float s = 0.f;
#pragma unroll
  for (int j = 0; j < 8; ++j)
    s += partial2[(size_t)(b * 8 + j) * PF2 + kc * 80 + 64];
  Sfin[b * 128 + kc] = s;
}

__global__ __launch_bounds__(256) void k_red_b(
    const float* __restrict__ partial2, const float* __restrict__ Sfin,
    float* __restrict__ kvn)
{
  const int bid = blockIdx.x;               // 64 = 2b x 32
  const int chunk = bid & 31, b = bid >> 5;
  const int e = chunk * 256 + threadIdx.x;  // < 8192
  const int kc = e >> 6, dv = e & 63;
  float s = 0.f;
#pragma unroll
  for (int j = 0; j < 8; ++j)
    s += partial2[(size_t)(b * 8 + j) * PF2 + kc * 80 + dv];
  kvn[(size_t)b * 8192 + e] = s / (Sfin[b * 128 + kc] * (1.f + 1e-6f));
}

// ---------------------------------------------------------------------------
// k_out2: out[n][c] = qsm[n][.] · kvn (unchanged).
// ---------------------------------------------------------------------------
__global__ __launch_bounds__(256) void k_out2(
    const uint* __restrict__ qsm, const float* __restrict__ kvn,
    float* __restrict__ out)
{
  const int t = threadIdx.x, lane = t & 63;
  const int w = __builtin_amdgcn_readfirstlane(t >> 6);
  const int bid = blockIdx.x;
  const int b  = bid / 1728;
  const int n0 = (bid % 1728) * 64;

  const uint* qp = qsm + ((size_t)b * NPOS + n0 + lane) * 64 + w * 16;
  uint q[16];
  *(uint4*)&q[0]  = *(const uint4*)(qp);
  *(uint4*)&q[4]  = *(const uint4*)(qp + 4);
  *(uint4*)&q[8]  = *(const uint4*)(qp + 8);
  *(uint4*)&q[12] = *(const uint4*)(qp + 12);
  float qa[32];
#pragma unroll
  for (int j = 0; j < 16; ++j) {
    qa[2 * j]     = __uint_as_float(q[j] << 16);
    qa[2 * j + 1] = __uint_as_float(q[j] & 0xFFFF0000u);
  }

  float oa[64];
#pragma unroll
  for (int d = 0; d < 64; ++d) oa[d] = 0.f;
  const float* kvh = kvn + (size_t)b * 8192 + (size_t)(w * 32) * 64;
#pragma unroll
  for (int kc = 0; kc < 32; ++kc) {
    const float* kr = kvh + kc * 64;
#pragma unroll
    for (int d = 0; d < 64; ++d) oa[d] = fmaf(qa[kc], kr[d], oa[d]);
  }
  float* ob = out + (size_t)(b * CH + w * DV) * NPOS + n0 + lane;
#pragma unroll
  for (int d = 0; d < 64; ++d) ob[(size_t)d * NPOS] = oa[d];
}

// ---------------------------------------------------------------------------
extern "C" void kernel_launch(void* const* d_in, const int* in_sizes, int n_in,
                              void* d_out, int out_size, void* d_ws, size_t ws_size,
                              hipStream_t stream)
{
  const float* x  = (const float*)d_in[0];
  const float* Wq = (const float*)d_in[1];
  const float* Wk = (const float*)d_in[2];
  const float* Wv = (const float*)d_in[3];
  const float* bv = (const float*)d_in[4];
  float* out = (float*)d_out;
  float* ws  = (float*)d_ws;

  // ws (u32 words): Wqk2 32768 | qsm 14155776 | kvn 16384 | Sfin 256 |
  //                 partial2 16*PF2 | partials 2*nbh*PF2 | vbuf bf16
  ushort* Wqk2    = (ushort*)ws;
  uint*   qsm     = (uint*)(ws + 32768);
  float*  kvn     = ws + 32768 + 14155776;
  float*  Sfin    = kvn + 16384;
  float*  partial2= Sfin + 256;
  const size_t fixed0 = 32768 + 14155776 + 16384 + 256 + (size_t)16 * PF2;
  float*  partials = partial2 + 16 * PF2;

  const size_t wsf = ws_size / 4;
  static const int cand[][2] = {
    {128,48},{128,24},{64,24},{128,12},{64,12},{64,6},{32,6},{32,3}};
  int nbh = 32, ys = 3;
  for (int i = 0; i < 8; ++i) {
    const size_t need = fixed0 + (size_t)(2 * cand[i][0]) * PF2
                      + (size_t)cand[i][1] * 589824;
    if (need <= wsf) { nbh = cand[i][0]; ys = cand[i][1]; break; }
  }
  __hip_bfloat16* vbuf = (__hip_bfloat16*)(partials + (size_t)(2 * nbh) * PF2);

  k_prep2<<<256, 256, 0, stream>>>(Wq, Wk, Wqk2);

  const int nslab = 48 / ys;
  for (int s = 0; s < nslab; ++s) {
    k_conv<<<1152,    256, 0, stream>>>(x, Wv, bv, vbuf, s * ys, ys);
    k_fuse<<<2 * nbh, 512, 0, stream>>>(x, Wqk2, (const ushort*)vbuf, qsm,
                                        partials, s * ys, ys,
                                        (s == 0) ? 1 : 0, nbh);
  }
  k_red_a<<<640, 256, 0, stream>>>(partials, partial2, nbh);
  k_red_s<<<1,   256, 0, stream>>>(partial2, Sfin);
  k_red_b<<<64,  256, 0, stream>>>(partial2, Sfin, kvn);
  k_out2 <<<2 * 1728, 256, 0, stream>>>(qsm, kvn, out);
}